// Round 16
// baseline (69.285 us; speedup 1.0000x reference)
//
#include <hip/hip_runtime.h>

#define NN     3072   // nodes
#define IND    512    // input dim
#define NH     8      // heads
#define DH     64     // head dim
#define HDTOT  512    // NH*DH
#define NA     8      // angles
#define THALF  256    // HDTOT/2
#define DN     196608 // DH*NN
#define NZ     6      // attention j-split

typedef float f32x4 __attribute__((ext_vector_type(4)));
typedef short bf16x8 __attribute__((ext_vector_type(8)));
typedef unsigned int u32x2 __attribute__((ext_vector_type(2)));

// scalar RNE convert (bit-twiddle)
__device__ __forceinline__ unsigned short f2bf(float f) {
    union { float f; unsigned u; } a; a.f = f;
    unsigned u = a.u;
    return (unsigned short)((u + 0x7FFFu + ((u >> 16) & 1u)) >> 16);
}
// RNE pair-pack: 2x(round) + one v_perm_b32 merging the high halves.
__device__ __forceinline__ unsigned pack2(float a, float b) {
    union { float f; unsigned u; } ua, ub; ua.f = a; ub.f = b;
    unsigned ra = ua.u + 0x7FFFu + ((ua.u >> 16) & 1u);
    unsigned rb = ub.u + 0x7FFFu + ((ub.u >> 16) & 1u);
    return __builtin_amdgcn_perm(rb, ra, 0x07060302);  // {rb.hi16, ra.hi16}
}
__device__ __forceinline__ float ubits2f(unsigned u) {
    union { unsigned u; float f; } c; c.u = u; return c.f;
}

// ---------------------------------------------------------------------------
// k_prep: block 0 -> softmax(S) wave-parallel; blocks 1..768 -> x f32->bf16;
// blocks 769..1536 -> W transpose+convert to WTb[1536][512].
// ---------------------------------------------------------------------------
__global__ __launch_bounds__(256) void k_prep(
    const float* __restrict__ S, const float* __restrict__ x,
    const float* __restrict__ Wq, const float* __restrict__ Wk,
    const float* __restrict__ Wv,
    float* __restrict__ SM, unsigned short* __restrict__ xb,
    unsigned short* __restrict__ WTb)
{
    __shared__ float sh[32 * 33];
    const int b = blockIdx.x, t = threadIdx.x;
    if (b == 0) {
        const int wvp = t >> 6;
        const int ln  = t & 63;
        for (int a = wvp; a < NA; a += 4) {
            float4 v = *reinterpret_cast<const float4*>(&S[a * THALF + ln * 4]);
            float mx = fmaxf(fmaxf(v.x, v.y), fmaxf(v.z, v.w));
            #pragma unroll
            for (int m = 1; m < 64; m <<= 1) mx = fmaxf(mx, __shfl_xor(mx, m));
            float e0 = __expf(v.x - mx), e1 = __expf(v.y - mx);
            float e2 = __expf(v.z - mx), e3 = __expf(v.w - mx);
            float s = (e0 + e1) + (e2 + e3);
            #pragma unroll
            for (int m = 1; m < 64; m <<= 1) s += __shfl_xor(s, m);
            float inv = 1.0f / s;
            float4 o; o.x = e0 * inv; o.y = e1 * inv; o.z = e2 * inv; o.w = e3 * inv;
            *reinterpret_cast<float4*>(&SM[a * THALF + ln * 4]) = o;
        }
    } else if (b <= 768) {
        const size_t base = ((size_t)(b - 1) * 256 + t) * 8;
        float4 v0 = *reinterpret_cast<const float4*>(&x[base]);
        float4 v1 = *reinterpret_cast<const float4*>(&x[base + 4]);
        uint4 w;
        w.x = pack2(v0.x, v0.y); w.y = pack2(v0.z, v0.w);
        w.z = pack2(v1.x, v1.y); w.w = pack2(v1.z, v1.w);
        *reinterpret_cast<uint4*>(&xb[base]) = w;
    } else {
        const int b2 = b - 769;
        const int kt = b2 & 15, nt = b2 >> 4;
        const int k0 = kt * 32, n0 = nt * 32;
        const float* __restrict__ W = (n0 < 512) ? Wq : (n0 < 1024 ? Wk : Wv);
        const int nc0 = n0 & 511;
        const int r = t >> 5, c = t & 31;
        #pragma unroll
        for (int i = 0; i < 4; ++i)
            sh[(r + i * 8) * 33 + c] = W[(size_t)(k0 + r + i * 8) * HDTOT + nc0 + c];
        __syncthreads();
        #pragma unroll
        for (int i = 0; i < 4; ++i) {
            const int nr = r + i * 8;
            WTb[(size_t)(n0 + nr) * IND + k0 + c] = f2bf(sh[c * 33 + nr]);
        }
    }
}

// ---------------------------------------------------------------------------
// k_qkv_mfma: C[3072,1536] = xb @ W (bf16 MFMA, f32 accum), fused bias +
// rotation epilogue. BM=128, BN=64, BK=64, 4 waves (2x2), per-wave 64x32.
// Grid (24, 24). kt-loop capped at unroll 1 to keep the body L1I-resident.
// Outputs: Qb natural (PRE-SCALED by 0.125*log2e), KTb[h][j][d], VTb[h][d][n].
// ---------------------------------------------------------------------------
__global__ __launch_bounds__(256) void k_qkv_mfma(
    const unsigned short* __restrict__ xb,
    const unsigned short* __restrict__ WTb,
    const float* __restrict__ bq, const float* __restrict__ bk,
    const float* __restrict__ bv,
    const float* __restrict__ angles, const float* __restrict__ SM,
    unsigned short* __restrict__ Qb, unsigned short* __restrict__ KTb,
    unsigned short* __restrict__ VTb)
{
    __shared__ __align__(16) char lds[41472];
    char* At  = lds;                       // [128][64] bf16 swizzled (16 KB)
    char* Bt  = lds + 16384;               // [64][64]  bf16 swizzled (8 KB)
    float* Cs = (float*)lds;               // [128][65] f32 (aliases At/Bt)
    float* SMl = (float*)(lds + 33280);    // 2048 f32

    const int t = threadIdx.x;
    const int lane = t & 63;
    const int wv = t >> 6;
    const int wrow = wv >> 1, wcol = wv & 1;
    const int l15 = lane & 15, lg = lane >> 4;
    const int r8 = lane >> 3, c8 = lane & 7;

    const int m0 = blockIdx.x * 128;
    const int n0 = blockIdx.y * 64;
    const int mat = n0 >> 9;              // 0=Q 1=K 2=V
    const int c0 = n0 & 511;

    if (mat < 2) {
        #pragma unroll
        for (int r = 0; r < 8; ++r) SMl[r * 256 + t] = SM[r * 256 + t];
    }

    f32x4 acc[4][2];
    #pragma unroll
    for (int mf = 0; mf < 4; ++mf)
        #pragma unroll
        for (int nf = 0; nf < 2; ++nf)
            acc[mf][nf] = (f32x4){0.f, 0.f, 0.f, 0.f};

    #pragma unroll 1
    for (int kt = 0; kt < 8; ++kt) {
        __syncthreads();
        #pragma unroll
        for (int i = 0; i < 4; ++i) {
            const int row = wv * 32 + i * 8 + r8;
            const unsigned short* src =
                xb + (size_t)(m0 + row) * IND + kt * 64 + (c8 ^ (row & 7)) * 8;
            __builtin_amdgcn_global_load_lds(
                (const __attribute__((address_space(1))) unsigned int*)src,
                (__attribute__((address_space(3))) unsigned int*)(At + (wv * 32 + i * 8) * 128),
                16, 0, 0);
        }
        #pragma unroll
        for (int i = 0; i < 2; ++i) {
            const int row = wv * 16 + i * 8 + r8;
            const unsigned short* src =
                WTb + (size_t)(n0 + row) * IND + kt * 64 + (c8 ^ (row & 7)) * 8;
            __builtin_amdgcn_global_load_lds(
                (const __attribute__((address_space(1))) unsigned int*)src,
                (__attribute__((address_space(3))) unsigned int*)(Bt + (wv * 16 + i * 8) * 128),
                16, 0, 0);
        }
        __syncthreads();
        #pragma unroll
        for (int ks = 0; ks < 2; ++ks) {
            bf16x8 af[4], bfr[2];
            #pragma unroll
            for (int mf = 0; mf < 4; ++mf) {
                const int row = wrow * 64 + mf * 16 + l15;
                int off = row * 128 + ks * 64 + lg * 16;
                off ^= (row & 7) << 4;
                af[mf] = *reinterpret_cast<const bf16x8*>(At + off);
            }
            #pragma unroll
            for (int nf = 0; nf < 2; ++nf) {
                const int row = wcol * 32 + nf * 16 + l15;
                int off = row * 128 + ks * 64 + lg * 16;
                off ^= (row & 7) << 4;
                bfr[nf] = *reinterpret_cast<const bf16x8*>(Bt + off);
            }
            #pragma unroll
            for (int mf = 0; mf < 4; ++mf)
                #pragma unroll
                for (int nf = 0; nf < 2; ++nf)
                    acc[mf][nf] = __builtin_amdgcn_mfma_f32_16x16x32_bf16(
                        af[mf], bfr[nf], acc[mf][nf], 0, 0, 0);
        }
    }

    if (mat == 2) {
        // V: direct store from accumulators to VTb[h][d][n] (n-contiguous)
        #pragma unroll
        for (int nf = 0; nf < 2; ++nf) {
            const int cg = c0 + wcol * 32 + nf * 16 + l15;
            const float b = bv[cg];
            const int hV = cg >> 6, dd = cg & 63;
            #pragma unroll
            for (int mf = 0; mf < 4; ++mf) {
                const int nb = m0 + wrow * 64 + mf * 16 + lg * 4;
                u32x2 w;
                w.x = pack2(acc[mf][nf][0] + b, acc[mf][nf][1] + b);
                w.y = pack2(acc[mf][nf][2] + b, acc[mf][nf][3] + b);
                *reinterpret_cast<u32x2*>(&VTb[(size_t)hV * DN + (size_t)dd * NN + nb]) = w;
            }
        }
        return;
    }

    // Q/K: stage biased tile to Cs, then rotation epilogue
    __syncthreads();   // frag reads of At/Bt done before aliasing as Cs
    const float* __restrict__ bsv = mat ? bk : bq;
    #pragma unroll
    for (int nf = 0; nf < 2; ++nf) {
        const int colc = wcol * 32 + nf * 16 + l15;
        const float b = bsv[c0 + colc];
        #pragma unroll
        for (int mf = 0; mf < 4; ++mf) {
            const int rb = wrow * 64 + mf * 16 + lg * 4;
            #pragma unroll
            for (int r = 0; r < 4; ++r)
                Cs[(rb + r) * 65 + colc] = acc[mf][nf][r] + b;
        }
    }
    __syncthreads();

    const int ni0 = (t & 15) * 4;
    const int rbase = (t >> 4) * 8;
    const int pidx = (c0 + ni0) >> 1;
    const int hK = m0 / 384;
    const float QS = 0.1803368801111204f;   // 0.125 * log2(e), folded into Q

    #pragma unroll 1
    for (int rr = 0; rr < 8; ++rr) {
        const int row = rbase + rr;
        const int n = m0 + row;
        const float4 a0 = *reinterpret_cast<const float4*>(&angles[n * NA]);
        const float4 a1 = *reinterpret_cast<const float4*>(&angles[n * NA + 4]);
        float th0, th1;
        th0 = a0.x * SMl[0 * 256 + pidx];
        th0 = fmaf(a0.y, SMl[1 * 256 + pidx], th0);
        th0 = fmaf(a0.z, SMl[2 * 256 + pidx], th0);
        th0 = fmaf(a0.w, SMl[3 * 256 + pidx], th0);
        th0 = fmaf(a1.x, SMl[4 * 256 + pidx], th0);
        th0 = fmaf(a1.y, SMl[5 * 256 + pidx], th0);
        th0 = fmaf(a1.z, SMl[6 * 256 + pidx], th0);
        th0 = fmaf(a1.w, SMl[7 * 256 + pidx], th0);
        th1 = a0.x * SMl[0 * 256 + pidx + 1];
        th1 = fmaf(a0.y, SMl[1 * 256 + pidx + 1], th1);
        th1 = fmaf(a0.z, SMl[2 * 256 + pidx + 1], th1);
        th1 = fmaf(a0.w, SMl[3 * 256 + pidx + 1], th1);
        th1 = fmaf(a1.x, SMl[4 * 256 + pidx + 1], th1);
        th1 = fmaf(a1.y, SMl[5 * 256 + pidx + 1], th1);
        th1 = fmaf(a1.z, SMl[6 * 256 + pidx + 1], th1);
        th1 = fmaf(a1.w, SMl[7 * 256 + pidx + 1], th1);
        float s0, c0f, s1, c1f;
        __sincosf(th0, &s0, &c0f);
        __sincosf(th1, &s1, &c1f);
        float o[4];
        #pragma unroll
        for (int cc = 0; cc < 4; ++cc) {
            const int d = ni0 + cc;
            const int pd = (d < 32) ? (2 * d + 1) : (2 * (d - 32));
            float own = Cs[row * 65 + d];
            float pv  = Cs[row * 65 + pd];
            float q2  = (d < 32) ? -pv : pv;
            float ct  = (cc < 2) ? c0f : c1f;
            float st  = (cc < 2) ? s0 : s1;
            o[cc] = own * ct + q2 * st;
        }
        if (mat == 0) {
            u32x2 w;
            w.x = pack2(o[0] * QS, o[1] * QS);
            w.y = pack2(o[2] * QS, o[3] * QS);
            *reinterpret_cast<u32x2*>(&Qb[(size_t)n * HDTOT + c0 + ni0]) = w;
        } else {
            const int nn = n - hK * 384;
            const int dk = nn / 6;
            const int jb = (nn - dk * 6) * 512 + c0 + ni0;
            #pragma unroll
            for (int cc = 0; cc < 4; ++cc)
                KTb[(size_t)hK * DN + (size_t)(jb + cc) * 64 + dk] = f2bf(o[cc]);
        }
    }
}

// ---------------------------------------------------------------------------
// k_attn: MFMA attention, R15 structure (4-wave blocks, shared 16 KB K/V tile,
// 32 KB LDS, single-buffered, full-drain barriers, head-major XCD mapping).
// NEW: jj-loop capped at `#pragma unroll 1` — the fully-unrolled 8-tile body
// (~20+ KB) overflowed the shared 32 KB L1I; a ~2.5 KB rolled body stays
// I$-resident. No numeric change.
// ---------------------------------------------------------------------------
template<int TILES, bool PARTIAL>
__global__ __launch_bounds__(256) void k_attn(
    const unsigned short* __restrict__ Qb,
    const unsigned short* __restrict__ KTb,
    const unsigned short* __restrict__ VTb,
    float* __restrict__ outp, float* __restrict__ Dp)
{
    __shared__ __align__(16) char smem[32768];
    const int t = threadIdx.x;
    const int lane = t & 63;
    const int wv = t >> 6;                 // 0..3
    char* ktl = smem;                      // [64 j][64 d] bf16, swizzled (8 KB)
    char* vtl = smem + 8192;               // [64 d][64 j] bf16, swizzled (8 KB)
    char* ptw = smem + 16384 + wv * 4096;  // per-wave P [32 i][64 j] bf16, swizzled

    const int bid = blockIdx.x;
    const int h   = bid & 7;               // XCD-major: head == XCD slot
    const int rem = bid >> 3;
    const int qx  = rem % 24;
    const int z   = rem / 24;              // 0..NZ-1
    const int qbase = qx * 128;
    const int jt0 = z * TILES;
    const int l15 = lane & 15;
    const int lg = lane >> 4;
    const int r8 = lane >> 3;
    const int c8 = lane & 7;

    const float CLP = 7.2134752044448170f;   // 5 * log2(e)

    // hoisted swizzled-offset lane constants (row&7 == l15&7)
    const int X  = (l15 & 7) << 4;
    const int A0 = l15 * 128 + ((lg * 16) ^ X);
    const int A1 = l15 * 128 + ((64 + lg * 16) ^ X);
    const int W0 = l15 * 128 + ((lg * 8) ^ X);
    const int W1 = l15 * 128 + ((32 + lg * 8) ^ X);
    const int W2 = l15 * 128 + ((64 + lg * 8) ^ X);
    const int W3 = l15 * 128 + ((96 + lg * 8) ^ X);

    bf16x8 qf[2][2];
    #pragma unroll
    for (int im = 0; im < 2; ++im)
        #pragma unroll
        for (int ks = 0; ks < 2; ++ks) {
            const int i = qbase + wv * 32 + im * 16 + l15;
            qf[im][ks] = *reinterpret_cast<const bf16x8*>(
                Qb + (size_t)h * DN + (size_t)i * 64 + ks * 32 + lg * 8);
        }

    f32x4 oacc[2][4];
    #pragma unroll
    for (int im = 0; im < 2; ++im)
        #pragma unroll
        for (int db = 0; db < 4; ++db)
            oacc[im][db] = (f32x4){0.f, 0.f, 0.f, 0.f};
    float dpart[2] = {0.f, 0.f};

    #pragma unroll 1
    for (int jj = 0; jj < TILES; ++jj) {
        const int j0 = (jt0 + jj) * 64;
        // ---- stage K/V tile: 4 waves x 2 row-groups of 8 = 64 rows each
        #pragma unroll
        for (int cc = 0; cc < 2; ++cc) {
            const int row = wv * 16 + cc * 8 + r8;
            const int chunk = c8 ^ (row & 7);
            const unsigned short* srcK =
                KTb + (size_t)h * DN + (size_t)(j0 + row) * 64 + chunk * 8;
            __builtin_amdgcn_global_load_lds(
                (const __attribute__((address_space(1))) unsigned int*)srcK,
                (__attribute__((address_space(3))) unsigned int*)(ktl + (wv * 16 + cc * 8) * 128),
                16, 0, 0);
            const unsigned short* srcV =
                VTb + (size_t)h * DN + (size_t)row * NN + j0 + chunk * 8;
            __builtin_amdgcn_global_load_lds(
                (const __attribute__((address_space(1))) unsigned int*)srcV,
                (__attribute__((address_space(3))) unsigned int*)(vtl + (wv * 16 + cc * 8) * 128),
                16, 0, 0);
        }
        __syncthreads();   // drain stage -> tile visible to all waves

        // ---- score: S^T[j,i] over d (2 k-steps)
        f32x4 sac[2][4];
        #pragma unroll
        for (int im = 0; im < 2; ++im)
            #pragma unroll
            for (int jb = 0; jb < 4; ++jb)
                sac[im][jb] = (f32x4){0.f, 0.f, 0.f, 0.f};
        #pragma unroll
        for (int ks = 0; ks < 2; ++ks) {
            const int Aks = ks ? A1 : A0;
            bf16x8 kf[4];
            #pragma unroll
            for (int jb = 0; jb < 4; ++jb)
                kf[jb] = *reinterpret_cast<const bf16x8*>(ktl + Aks + jb * 2048);
            #pragma unroll
            for (int im = 0; im < 2; ++im)
                #pragma unroll
                for (int jb = 0; jb < 4; ++jb)
                    sac[im][jb] = __builtin_amdgcn_mfma_f32_16x16x32_bf16(
                        kf[jb], qf[im][ks], sac[im][jb], 0, 0, 0);
        }

        // ---- softmax piece -> P bf16 in per-wave LDS
        #pragma unroll
        for (int im = 0; im < 2; ++im) {
            #pragma unroll
            for (int jb = 0; jb < 4; ++jb) {
                float p[4];
                #pragma unroll
                for (int r = 0; r < 4; ++r) {
                    float sc = __builtin_amdgcn_fmed3f(sac[im][jb][r], -CLP, CLP);
                    p[r] = __builtin_amdgcn_exp2f(sc);
                }
                dpart[im] += (p[0] + p[1]) + (p[2] + p[3]);
                u32x2 w;
                w.x = pack2(p[0], p[1]);
                w.y = pack2(p[2], p[3]);
                const int aw = (jb == 0) ? W0 : (jb == 1) ? W1 : (jb == 2) ? W2 : W3;
                *reinterpret_cast<u32x2*>(ptw + aw + im * 2048) = w;
            }
        }

        // ---- PV: O^T[d,i] += V^T[d,j] * P[i][j]-as-B
        bf16x8 pf[2][2];
        #pragma unroll
        for (int im = 0; im < 2; ++im)
            #pragma unroll
            for (int js = 0; js < 2; ++js)
                pf[im][js] = *reinterpret_cast<const bf16x8*>(
                    ptw + (js ? A1 : A0) + im * 2048);
        #pragma unroll
        for (int js = 0; js < 2; ++js) {
            const int Ajs = js ? A1 : A0;
            #pragma unroll
            for (int db = 0; db < 4; ++db) {
                bf16x8 vf = *reinterpret_cast<const bf16x8*>(vtl + Ajs + db * 2048);
                #pragma unroll
                for (int im = 0; im < 2; ++im)
                    oacc[im][db] = __builtin_amdgcn_mfma_f32_16x16x32_bf16(
                        vf, pf[im][js], oacc[im][db], 0, 0, 0);
            }
        }
        __syncthreads();   // all waves done reading ktl/vtl before next stage
    }

    // ---- epilogue
    #pragma unroll
    for (int im = 0; im < 2; ++im) {
        float d = dpart[im];
        d += __shfl_xor(d, 16);
        d += __shfl_xor(d, 32);
        const int i = qbase + wv * 32 + im * 16 + l15;
        if (PARTIAL) {
            if (lg == 0) Dp[((size_t)z * NH + h) * NN + i] = d;
            unsigned short* Ob = (unsigned short*)outp;
            const size_t base = (((size_t)z * NH + h) * NN + i) * 64;
            #pragma unroll
            for (int db = 0; db < 4; ++db) {
                u32x2 w;
                w.x = pack2(oacc[im][db][0], oacc[im][db][1]);
                w.y = pack2(oacc[im][db][2], oacc[im][db][3]);
                *reinterpret_cast<u32x2*>(&Ob[base + db * 16 + lg * 4]) = w;
            }
        } else {
            const float inv = 1.0f / d;
            #pragma unroll
            for (int db = 0; db < 4; ++db) {
                float4 o;
                o.x = oacc[im][db][0] * inv; o.y = oacc[im][db][1] * inv;
                o.z = oacc[im][db][2] * inv; o.w = oacc[im][db][3] * inv;
                *reinterpret_cast<float4*>(
                    &outp[(size_t)i * HDTOT + h * DH + db * 16 + lg * 4]) = o;
            }
        }
    }
}

// ---------------------------------------------------------------------------
// k_reduce: out = (sum_z Opart_bf16) / (sum_z Dpart). Head-major mapping
// (h = bid % 8) so partial reads hit the writer XCD's L2.
// ---------------------------------------------------------------------------
__global__ __launch_bounds__(256) void k_reduce(
    const unsigned short* __restrict__ Ob, const float* __restrict__ Dp,
    float* __restrict__ out, int nz)
{
    const int b  = blockIdx.x;            // 0..1535
    const int t  = threadIdx.x;
    const int h  = b & 7;
    const int r  = b >> 3;                // 0..191
    const int q  = r * 256 + t;           // 0..49151
    const int i  = q >> 4;
    const int dc = q & 15;

    float o0 = 0.f, o1 = 0.f, o2 = 0.f, o3 = 0.f;
    float D = 0.f;
    for (int zz = 0; zz < nz; ++zz) {
        u32x2 v = *reinterpret_cast<const u32x2*>(
            &Ob[(((size_t)zz * NH + h) * NN + i) * 64 + dc * 4]);
        o0 += ubits2f(v.x << 16);
        o1 += ubits2f(v.x & 0xFFFF0000u);
        o2 += ubits2f(v.y << 16);
        o3 += ubits2f(v.y & 0xFFFF0000u);
        D += Dp[((size_t)zz * NH + h) * NN + i];
    }
    const float inv = 1.0f / D;
    float4 w;
    w.x = o0 * inv; w.y = o1 * inv; w.z = o2 * inv; w.w = o3 * inv;
    *reinterpret_cast<float4*>(&out[(size_t)i * HDTOT + h * 64 + dc * 4]) = w;
}

// ---------------------------------------------------------------------------
extern "C" void kernel_launch(void* const* d_in, const int* in_sizes, int n_in,
                              void* d_out, int out_size, void* d_ws, size_t ws_size,
                              hipStream_t stream)
{
    const float* x      = (const float*)d_in[0];
    const float* angles = (const float*)d_in[1];
    const float* Wq     = (const float*)d_in[2];
    const float* bq     = (const float*)d_in[3];
    const float* Wk     = (const float*)d_in[4];
    const float* bk     = (const float*)d_in[5];
    const float* Wv     = (const float*)d_in[6];
    const float* bv     = (const float*)d_in[7];
    const float* S      = (const float*)d_in[8];
    float* out = (float*)d_out;

    float* ws = (float*)d_ws;
    float* SM = ws;                                        // 4096 f32
    unsigned short* xb  = (unsigned short*)(ws + 4096);    // 3072*512 bf16
    unsigned short* WTb = xb + (size_t)NN * IND;           // 1536*512 bf16
    unsigned short* Qb  = WTb + (size_t)1536 * IND;        // 3 MB each
    unsigned short* KTb = Qb + (size_t)NN * HDTOT;
    unsigned short* VTb = KTb + (size_t)NN * HDTOT;
    unsigned short* Opart = VTb + (size_t)NN * HDTOT;      // NZ*8*3072*64 bf16
    float* Dpart = (float*)(Opart + (size_t)NZ * NH * NN * DH);  // NZ*8*3072 f32
    const size_t need = (size_t)((char*)(Dpart + (size_t)NZ * NH * NN) - (char*)d_ws);

    k_prep<<<1537, 256, 0, stream>>>(S, x, Wq, Wk, Wv, SM, xb, WTb);
    k_qkv_mfma<<<dim3(24, 24), 256, 0, stream>>>(xb, WTb, bq, bk, bv,
                                                 angles, SM, Qb, KTb, VTb);
    if (ws_size >= need) {
        k_attn<48 / NZ, true><<<8 * 24 * NZ, 256, 0, stream>>>(Qb, KTb, VTb,
                                                               (float*)Opart, Dpart);
        k_reduce<<<1536, 256, 0, stream>>>(Opart, Dpart, out, NZ);
    } else {
        k_attn<48, false><<<8 * 24, 256, 0, stream>>>(Qb, KTb, VTb, out, nullptr);
    }
}

// Round 17
// 67.302 us; speedup vs baseline: 1.0295x; 1.0295x over previous
//
#include <hip/hip_runtime.h>

#define NN     3072   // nodes
#define IND    512    // input dim
#define NH     8      // heads
#define DH     64     // head dim
#define HDTOT  512    // NH*DH
#define NA     8      // angles
#define THALF  256    // HDTOT/2
#define DN     196608 // DH*NN
#define NZ     4      // attention j-split

typedef float f32x4 __attribute__((ext_vector_type(4)));
typedef short bf16x8 __attribute__((ext_vector_type(8)));
typedef unsigned int u32x2 __attribute__((ext_vector_type(2)));

// scalar RNE convert (bit-twiddle)
__device__ __forceinline__ unsigned short f2bf(float f) {
    union { float f; unsigned u; } a; a.f = f;
    unsigned u = a.u;
    return (unsigned short)((u + 0x7FFFu + ((u >> 16) & 1u)) >> 16);
}
// RNE pair-pack: 2x(round) + one v_perm_b32 merging the high halves.
__device__ __forceinline__ unsigned pack2(float a, float b) {
    union { float f; unsigned u; } ua, ub; ua.f = a; ub.f = b;
    unsigned ra = ua.u + 0x7FFFu + ((ua.u >> 16) & 1u);
    unsigned rb = ub.u + 0x7FFFu + ((ub.u >> 16) & 1u);
    return __builtin_amdgcn_perm(rb, ra, 0x07060302);  // {rb.hi16, ra.hi16}
}
__device__ __forceinline__ float ubits2f(unsigned u) {
    union { unsigned u; float f; } c; c.u = u; return c.f;
}

// ---------------------------------------------------------------------------
// k_prep: block 0 -> softmax(S) wave-parallel; blocks 1..768 -> x f32->bf16;
// blocks 769..1536 -> W transpose+convert to WTb[1536][512].
// ---------------------------------------------------------------------------
__global__ __launch_bounds__(256) void k_prep(
    const float* __restrict__ S, const float* __restrict__ x,
    const float* __restrict__ Wq, const float* __restrict__ Wk,
    const float* __restrict__ Wv,
    float* __restrict__ SM, unsigned short* __restrict__ xb,
    unsigned short* __restrict__ WTb)
{
    __shared__ float sh[32 * 33];
    const int b = blockIdx.x, t = threadIdx.x;
    if (b == 0) {
        const int wvp = t >> 6;
        const int ln  = t & 63;
        for (int a = wvp; a < NA; a += 4) {
            float4 v = *reinterpret_cast<const float4*>(&S[a * THALF + ln * 4]);
            float mx = fmaxf(fmaxf(v.x, v.y), fmaxf(v.z, v.w));
            #pragma unroll
            for (int m = 1; m < 64; m <<= 1) mx = fmaxf(mx, __shfl_xor(mx, m));
            float e0 = __expf(v.x - mx), e1 = __expf(v.y - mx);
            float e2 = __expf(v.z - mx), e3 = __expf(v.w - mx);
            float s = (e0 + e1) + (e2 + e3);
            #pragma unroll
            for (int m = 1; m < 64; m <<= 1) s += __shfl_xor(s, m);
            float inv = 1.0f / s;
            float4 o; o.x = e0 * inv; o.y = e1 * inv; o.z = e2 * inv; o.w = e3 * inv;
            *reinterpret_cast<float4*>(&SM[a * THALF + ln * 4]) = o;
        }
    } else if (b <= 768) {
        const size_t base = ((size_t)(b - 1) * 256 + t) * 8;
        float4 v0 = *reinterpret_cast<const float4*>(&x[base]);
        float4 v1 = *reinterpret_cast<const float4*>(&x[base + 4]);
        uint4 w;
        w.x = pack2(v0.x, v0.y); w.y = pack2(v0.z, v0.w);
        w.z = pack2(v1.x, v1.y); w.w = pack2(v1.z, v1.w);
        *reinterpret_cast<uint4*>(&xb[base]) = w;
    } else {
        const int b2 = b - 769;
        const int kt = b2 & 15, nt = b2 >> 4;
        const int k0 = kt * 32, n0 = nt * 32;
        const float* __restrict__ W = (n0 < 512) ? Wq : (n0 < 1024 ? Wk : Wv);
        const int nc0 = n0 & 511;
        const int r = t >> 5, c = t & 31;
        #pragma unroll
        for (int i = 0; i < 4; ++i)
            sh[(r + i * 8) * 33 + c] = W[(size_t)(k0 + r + i * 8) * HDTOT + nc0 + c];
        __syncthreads();
        #pragma unroll
        for (int i = 0; i < 4; ++i) {
            const int nr = r + i * 8;
            WTb[(size_t)(n0 + nr) * IND + k0 + c] = f2bf(sh[c * 33 + nr]);
        }
    }
}

// ---------------------------------------------------------------------------
// k_qkv_mfma: C[3072,1536] = xb @ W (bf16 MFMA, f32 accum), fused bias +
// rotation epilogue. BM=128, BN=64, BK=64, 4 waves (2x2), per-wave 64x32.
// 1D grid 576, COLUMN-MAJOR XCD mapping: y = (bid%8) + 8*((bid/8)%3) so each
// XCD owns 3 fixed 64-col tiles (one per Q/K/V matrix; WTb slice 192 KB) and
// the shared xb (3 MB) -> per-XCD working set 3.2 MB fits the 4 MB L2.
// Outputs: Qb natural (PRE-SCALED by 0.125*log2e), KTb[h][j][d], VTb[h][d][n].
// ---------------------------------------------------------------------------
__global__ __launch_bounds__(256) void k_qkv_mfma(
    const unsigned short* __restrict__ xb,
    const unsigned short* __restrict__ WTb,
    const float* __restrict__ bq, const float* __restrict__ bk,
    const float* __restrict__ bv,
    const float* __restrict__ angles, const float* __restrict__ SM,
    unsigned short* __restrict__ Qb, unsigned short* __restrict__ KTb,
    unsigned short* __restrict__ VTb)
{
    __shared__ __align__(16) char lds[41472];
    char* At  = lds;                       // [128][64] bf16 swizzled (16 KB)
    char* Bt  = lds + 16384;               // [64][64]  bf16 swizzled (8 KB)
    float* Cs = (float*)lds;               // [128][65] f32 (aliases At/Bt)
    float* SMl = (float*)(lds + 33280);    // 2048 f32

    const int t = threadIdx.x;
    const int lane = t & 63;
    const int wv = t >> 6;
    const int wrow = wv >> 1, wcol = wv & 1;
    const int l15 = lane & 15, lg = lane >> 4;
    const int r8 = lane >> 3, c8 = lane & 7;

    const int bid = blockIdx.x;            // 0..575
    const int ytile = (bid & 7) + 8 * ((bid >> 3) % 3);   // 0..23, XCD-major
    const int m0 = (bid / 24) * 128;
    const int n0 = ytile * 64;
    const int mat = n0 >> 9;              // 0=Q 1=K 2=V
    const int c0 = n0 & 511;

    if (mat < 2) {
        #pragma unroll
        for (int r = 0; r < 8; ++r) SMl[r * 256 + t] = SM[r * 256 + t];
    }

    f32x4 acc[4][2];
    #pragma unroll
    for (int mf = 0; mf < 4; ++mf)
        #pragma unroll
        for (int nf = 0; nf < 2; ++nf)
            acc[mf][nf] = (f32x4){0.f, 0.f, 0.f, 0.f};

    #pragma unroll 1
    for (int kt = 0; kt < 8; ++kt) {
        __syncthreads();
        #pragma unroll
        for (int i = 0; i < 4; ++i) {
            const int row = wv * 32 + i * 8 + r8;
            const unsigned short* src =
                xb + (size_t)(m0 + row) * IND + kt * 64 + (c8 ^ (row & 7)) * 8;
            __builtin_amdgcn_global_load_lds(
                (const __attribute__((address_space(1))) unsigned int*)src,
                (__attribute__((address_space(3))) unsigned int*)(At + (wv * 32 + i * 8) * 128),
                16, 0, 0);
        }
        #pragma unroll
        for (int i = 0; i < 2; ++i) {
            const int row = wv * 16 + i * 8 + r8;
            const unsigned short* src =
                WTb + (size_t)(n0 + row) * IND + kt * 64 + (c8 ^ (row & 7)) * 8;
            __builtin_amdgcn_global_load_lds(
                (const __attribute__((address_space(1))) unsigned int*)src,
                (__attribute__((address_space(3))) unsigned int*)(Bt + (wv * 16 + i * 8) * 128),
                16, 0, 0);
        }
        __syncthreads();
        #pragma unroll
        for (int ks = 0; ks < 2; ++ks) {
            bf16x8 af[4], bfr[2];
            #pragma unroll
            for (int mf = 0; mf < 4; ++mf) {
                const int row = wrow * 64 + mf * 16 + l15;
                int off = row * 128 + ks * 64 + lg * 16;
                off ^= (row & 7) << 4;
                af[mf] = *reinterpret_cast<const bf16x8*>(At + off);
            }
            #pragma unroll
            for (int nf = 0; nf < 2; ++nf) {
                const int row = wcol * 32 + nf * 16 + l15;
                int off = row * 128 + ks * 64 + lg * 16;
                off ^= (row & 7) << 4;
                bfr[nf] = *reinterpret_cast<const bf16x8*>(Bt + off);
            }
            #pragma unroll
            for (int mf = 0; mf < 4; ++mf)
                #pragma unroll
                for (int nf = 0; nf < 2; ++nf)
                    acc[mf][nf] = __builtin_amdgcn_mfma_f32_16x16x32_bf16(
                        af[mf], bfr[nf], acc[mf][nf], 0, 0, 0);
        }
    }

    if (mat == 2) {
        // V: direct store from accumulators to VTb[h][d][n] (n-contiguous)
        #pragma unroll
        for (int nf = 0; nf < 2; ++nf) {
            const int cg = c0 + wcol * 32 + nf * 16 + l15;
            const float b = bv[cg];
            const int hV = cg >> 6, dd = cg & 63;
            #pragma unroll
            for (int mf = 0; mf < 4; ++mf) {
                const int nb = m0 + wrow * 64 + mf * 16 + lg * 4;
                u32x2 w;
                w.x = pack2(acc[mf][nf][0] + b, acc[mf][nf][1] + b);
                w.y = pack2(acc[mf][nf][2] + b, acc[mf][nf][3] + b);
                *reinterpret_cast<u32x2*>(&VTb[(size_t)hV * DN + (size_t)dd * NN + nb]) = w;
            }
        }
        return;
    }

    // Q/K: stage biased tile to Cs, then rotation epilogue
    __syncthreads();   // frag reads of At/Bt done before aliasing as Cs
    const float* __restrict__ bsv = mat ? bk : bq;
    #pragma unroll
    for (int nf = 0; nf < 2; ++nf) {
        const int colc = wcol * 32 + nf * 16 + l15;
        const float b = bsv[c0 + colc];
        #pragma unroll
        for (int mf = 0; mf < 4; ++mf) {
            const int rb = wrow * 64 + mf * 16 + lg * 4;
            #pragma unroll
            for (int r = 0; r < 4; ++r)
                Cs[(rb + r) * 65 + colc] = acc[mf][nf][r] + b;
        }
    }
    __syncthreads();

    const int ni0 = (t & 15) * 4;
    const int rbase = (t >> 4) * 8;
    const int pidx = (c0 + ni0) >> 1;
    const int hK = m0 / 384;
    const float QS = 0.1803368801111204f;   // 0.125 * log2(e), folded into Q

    #pragma unroll 1
    for (int rr = 0; rr < 8; ++rr) {
        const int row = rbase + rr;
        const int n = m0 + row;
        const float4 a0 = *reinterpret_cast<const float4*>(&angles[n * NA]);
        const float4 a1 = *reinterpret_cast<const float4*>(&angles[n * NA + 4]);
        float th0, th1;
        th0 = a0.x * SMl[0 * 256 + pidx];
        th0 = fmaf(a0.y, SMl[1 * 256 + pidx], th0);
        th0 = fmaf(a0.z, SMl[2 * 256 + pidx], th0);
        th0 = fmaf(a0.w, SMl[3 * 256 + pidx], th0);
        th0 = fmaf(a1.x, SMl[4 * 256 + pidx], th0);
        th0 = fmaf(a1.y, SMl[5 * 256 + pidx], th0);
        th0 = fmaf(a1.z, SMl[6 * 256 + pidx], th0);
        th0 = fmaf(a1.w, SMl[7 * 256 + pidx], th0);
        th1 = a0.x * SMl[0 * 256 + pidx + 1];
        th1 = fmaf(a0.y, SMl[1 * 256 + pidx + 1], th1);
        th1 = fmaf(a0.z, SMl[2 * 256 + pidx + 1], th1);
        th1 = fmaf(a0.w, SMl[3 * 256 + pidx + 1], th1);
        th1 = fmaf(a1.x, SMl[4 * 256 + pidx + 1], th1);
        th1 = fmaf(a1.y, SMl[5 * 256 + pidx + 1], th1);
        th1 = fmaf(a1.z, SMl[6 * 256 + pidx + 1], th1);
        th1 = fmaf(a1.w, SMl[7 * 256 + pidx + 1], th1);
        float s0, c0f, s1, c1f;
        __sincosf(th0, &s0, &c0f);
        __sincosf(th1, &s1, &c1f);
        float o[4];
        #pragma unroll
        for (int cc = 0; cc < 4; ++cc) {
            const int d = ni0 + cc;
            const int pd = (d < 32) ? (2 * d + 1) : (2 * (d - 32));
            float own = Cs[row * 65 + d];
            float pv  = Cs[row * 65 + pd];
            float q2  = (d < 32) ? -pv : pv;
            float ct  = (cc < 2) ? c0f : c1f;
            float st  = (cc < 2) ? s0 : s1;
            o[cc] = own * ct + q2 * st;
        }
        if (mat == 0) {
            u32x2 w;
            w.x = pack2(o[0] * QS, o[1] * QS);
            w.y = pack2(o[2] * QS, o[3] * QS);
            *reinterpret_cast<u32x2*>(&Qb[(size_t)n * HDTOT + c0 + ni0]) = w;
        } else {
            const int nn = n - hK * 384;
            const int dk = nn / 6;
            const int jb = (nn - dk * 6) * 512 + c0 + ni0;
            #pragma unroll
            for (int cc = 0; cc < 4; ++cc)
                KTb[(size_t)hK * DN + (size_t)(jb + cc) * 64 + dk] = f2bf(o[cc]);
        }
    }
}

// ---------------------------------------------------------------------------
// k_attn: best-measured config (R12): 2-WAVE blocks (128 threads, 64 Q-rows),
// 24 KB LDS, single-buffered K/V tile, full-drain barriers, NZ=4 — PLUS
// head-major XCD mapping (h = bid%8) so each XCD's K/V working set (1.5 MB)
// is L2-resident. Hoisted swizzled offsets, med3+exp2 softmax (Q pre-scaled),
// perm-pack, bf16 partials.
// ---------------------------------------------------------------------------
template<int TILES, bool PARTIAL>
__global__ __launch_bounds__(128) void k_attn(
    const unsigned short* __restrict__ Qb,
    const unsigned short* __restrict__ KTb,
    const unsigned short* __restrict__ VTb,
    float* __restrict__ outp, float* __restrict__ Dp)
{
    __shared__ __align__(16) char smem[24576];
    const int t = threadIdx.x;
    const int lane = t & 63;
    const int wv = t >> 6;                 // 0..1
    char* ktl = smem;                      // [64 j][64 d] bf16, swizzled (8 KB)
    char* vtl = smem + 8192;               // [64 d][64 j] bf16, swizzled (8 KB)
    char* ptw = smem + 16384 + wv * 4096;  // per-wave P [32 i][64 j] bf16, swizzled

    const int bid = blockIdx.x;
    const int h   = bid & 7;               // XCD-major: head == XCD slot
    const int rem = bid >> 3;
    const int qx  = rem % 48;
    const int z   = rem / 48;              // 0..NZ-1
    const int qbase = qx * 64;
    const int jt0 = z * TILES;
    const int l15 = lane & 15;
    const int lg = lane >> 4;
    const int r8 = lane >> 3;
    const int c8 = lane & 7;

    const float CLP = 7.2134752044448170f;   // 5 * log2(e)

    // hoisted swizzled-offset lane constants (row&7 == l15&7)
    const int X  = (l15 & 7) << 4;
    const int A0 = l15 * 128 + ((lg * 16) ^ X);
    const int A1 = l15 * 128 + ((64 + lg * 16) ^ X);
    const int W0 = l15 * 128 + ((lg * 8) ^ X);
    const int W1 = l15 * 128 + ((32 + lg * 8) ^ X);
    const int W2 = l15 * 128 + ((64 + lg * 8) ^ X);
    const int W3 = l15 * 128 + ((96 + lg * 8) ^ X);

    bf16x8 qf[2][2];
    #pragma unroll
    for (int im = 0; im < 2; ++im)
        #pragma unroll
        for (int ks = 0; ks < 2; ++ks) {
            const int i = qbase + wv * 32 + im * 16 + l15;
            qf[im][ks] = *reinterpret_cast<const bf16x8*>(
                Qb + (size_t)h * DN + (size_t)i * 64 + ks * 32 + lg * 8);
        }

    f32x4 oacc[2][4];
    #pragma unroll
    for (int im = 0; im < 2; ++im)
        #pragma unroll
        for (int db = 0; db < 4; ++db)
            oacc[im][db] = (f32x4){0.f, 0.f, 0.f, 0.f};
    float dpart[2] = {0.f, 0.f};

    #pragma unroll 1
    for (int jj = 0; jj < TILES; ++jj) {
        const int j0 = (jt0 + jj) * 64;
        // ---- stage K/V tile: 2 waves x 4 row-groups of 8 = 64 rows each
        #pragma unroll
        for (int cc = 0; cc < 4; ++cc) {
            const int row = wv * 32 + cc * 8 + r8;
            const int chunk = c8 ^ (row & 7);
            const unsigned short* srcK =
                KTb + (size_t)h * DN + (size_t)(j0 + row) * 64 + chunk * 8;
            __builtin_amdgcn_global_load_lds(
                (const __attribute__((address_space(1))) unsigned int*)srcK,
                (__attribute__((address_space(3))) unsigned int*)(ktl + (wv * 32 + cc * 8) * 128),
                16, 0, 0);
            const unsigned short* srcV =
                VTb + (size_t)h * DN + (size_t)row * NN + j0 + chunk * 8;
            __builtin_amdgcn_global_load_lds(
                (const __attribute__((address_space(1))) unsigned int*)srcV,
                (__attribute__((address_space(3))) unsigned int*)(vtl + (wv * 32 + cc * 8) * 128),
                16, 0, 0);
        }
        __syncthreads();   // drain stage -> tile visible to both waves

        // ---- score: S^T[j,i] over d (2 k-steps)
        f32x4 sac[2][4];
        #pragma unroll
        for (int im = 0; im < 2; ++im)
            #pragma unroll
            for (int jb = 0; jb < 4; ++jb)
                sac[im][jb] = (f32x4){0.f, 0.f, 0.f, 0.f};
        #pragma unroll
        for (int ks = 0; ks < 2; ++ks) {
            const int Aks = ks ? A1 : A0;
            bf16x8 kf[4];
            #pragma unroll
            for (int jb = 0; jb < 4; ++jb)
                kf[jb] = *reinterpret_cast<const bf16x8*>(ktl + Aks + jb * 2048);
            #pragma unroll
            for (int im = 0; im < 2; ++im)
                #pragma unroll
                for (int jb = 0; jb < 4; ++jb)
                    sac[im][jb] = __builtin_amdgcn_mfma_f32_16x16x32_bf16(
                        kf[jb], qf[im][ks], sac[im][jb], 0, 0, 0);
        }

        // ---- softmax piece -> P bf16 in per-wave LDS
        #pragma unroll
        for (int im = 0; im < 2; ++im) {
            #pragma unroll
            for (int jb = 0; jb < 4; ++jb) {
                float p[4];
                #pragma unroll
                for (int r = 0; r < 4; ++r) {
                    float sc = __builtin_amdgcn_fmed3f(sac[im][jb][r], -CLP, CLP);
                    p[r] = __builtin_amdgcn_exp2f(sc);
                }
                dpart[im] += (p[0] + p[1]) + (p[2] + p[3]);
                u32x2 w;
                w.x = pack2(p[0], p[1]);
                w.y = pack2(p[2], p[3]);
                const int aw = (jb == 0) ? W0 : (jb == 1) ? W1 : (jb == 2) ? W2 : W3;
                *reinterpret_cast<u32x2*>(ptw + aw + im * 2048) = w;
            }
        }

        // ---- PV: O^T[d,i] += V^T[d,j] * P[i][j]-as-B
        bf16x8 pf[2][2];
        #pragma unroll
        for (int im = 0; im < 2; ++im)
            #pragma unroll
            for (int js = 0; js < 2; ++js)
                pf[im][js] = *reinterpret_cast<const bf16x8*>(
                    ptw + (js ? A1 : A0) + im * 2048);
        #pragma unroll
        for (int js = 0; js < 2; ++js) {
            const int Ajs = js ? A1 : A0;
            #pragma unroll
            for (int db = 0; db < 4; ++db) {
                bf16x8 vf = *reinterpret_cast<const bf16x8*>(vtl + Ajs + db * 2048);
                #pragma unroll
                for (int im = 0; im < 2; ++im)
                    oacc[im][db] = __builtin_amdgcn_mfma_f32_16x16x32_bf16(
                        vf, pf[im][js], oacc[im][db], 0, 0, 0);
            }
        }
        __syncthreads();   // both waves done reading ktl/vtl before next stage
    }

    // ---- epilogue
    #pragma unroll
    for (int im = 0; im < 2; ++im) {
        float d = dpart[im];
        d += __shfl_xor(d, 16);
        d += __shfl_xor(d, 32);
        const int i = qbase + wv * 32 + im * 16 + l15;
        if (PARTIAL) {
            if (lg == 0) Dp[((size_t)z * NH + h) * NN + i] = d;
            unsigned short* Ob = (unsigned short*)outp;
            const size_t base = (((size_t)z * NH + h) * NN + i) * 64;
            #pragma unroll
            for (int db = 0; db < 4; ++db) {
                u32x2 w;
                w.x = pack2(oacc[im][db][0], oacc[im][db][1]);
                w.y = pack2(oacc[im][db][2], oacc[im][db][3]);
                *reinterpret_cast<u32x2*>(&Ob[base + db * 16 + lg * 4]) = w;
            }
        } else {
            const float inv = 1.0f / d;
            #pragma unroll
            for (int db = 0; db < 4; ++db) {
                float4 o;
                o.x = oacc[im][db][0] * inv; o.y = oacc[im][db][1] * inv;
                o.z = oacc[im][db][2] * inv; o.w = oacc[im][db][3] * inv;
                *reinterpret_cast<float4*>(
                    &outp[(size_t)i * HDTOT + h * DH + db * 16 + lg * 4]) = o;
            }
        }
    }
}

// ---------------------------------------------------------------------------
// k_reduce: out = (sum_z Opart_bf16) / (sum_z Dpart). Head-major mapping
// (h = bid % 8) so partial reads hit the writer XCD's L2.
// ---------------------------------------------------------------------------
__global__ __launch_bounds__(256) void k_reduce(
    const unsigned short* __restrict__ Ob, const float* __restrict__ Dp,
    float* __restrict__ out, int nz)
{
    const int b  = blockIdx.x;            // 0..1535
    const int t  = threadIdx.x;
    const int h  = b & 7;
    const int r  = b >> 3;                // 0..191
    const int q  = r * 256 + t;           // 0..49151
    const int i  = q >> 4;
    const int dc = q & 15;

    float o0 = 0.f, o1 = 0.f, o2 = 0.f, o3 = 0.f;
    float D = 0.f;
    for (int zz = 0; zz < nz; ++zz) {
        u32x2 v = *reinterpret_cast<const u32x2*>(
            &Ob[(((size_t)zz * NH + h) * NN + i) * 64 + dc * 4]);
        o0 += ubits2f(v.x << 16);
        o1 += ubits2f(v.x & 0xFFFF0000u);
        o2 += ubits2f(v.y << 16);
        o3 += ubits2f(v.y & 0xFFFF0000u);
        D += Dp[((size_t)zz * NH + h) * NN + i];
    }
    const float inv = 1.0f / D;
    float4 w;
    w.x = o0 * inv; w.y = o1 * inv; w.z = o2 * inv; w.w = o3 * inv;
    *reinterpret_cast<float4*>(&out[(size_t)i * HDTOT + h * 64 + dc * 4]) = w;
}

// ---------------------------------------------------------------------------
extern "C" void kernel_launch(void* const* d_in, const int* in_sizes, int n_in,
                              void* d_out, int out_size, void* d_ws, size_t ws_size,
                              hipStream_t stream)
{
    const float* x      = (const float*)d_in[0];
    const float* angles = (const float*)d_in[1];
    const float* Wq     = (const float*)d_in[2];
    const float* bq     = (const float*)d_in[3];
    const float* Wk     = (const float*)d_in[4];
    const float* bk     = (const float*)d_in[5];
    const float* Wv     = (const float*)d_in[6];
    const float* bv     = (const float*)d_in[7];
    const float* S      = (const float*)d_in[8];
    float* out = (float*)d_out;

    float* ws = (float*)d_ws;
    float* SM = ws;                                        // 4096 f32
    unsigned short* xb  = (unsigned short*)(ws + 4096);    // 3072*512 bf16
    unsigned short* WTb = xb + (size_t)NN * IND;           // 1536*512 bf16
    unsigned short* Qb  = WTb + (size_t)1536 * IND;        // 3 MB each
    unsigned short* KTb = Qb + (size_t)NN * HDTOT;
    unsigned short* VTb = KTb + (size_t)NN * HDTOT;
    unsigned short* Opart = VTb + (size_t)NN * HDTOT;      // NZ*8*3072*64 bf16
    float* Dpart = (float*)(Opart + (size_t)NZ * NH * NN * DH);  // NZ*8*3072 f32
    const size_t need = (size_t)((char*)(Dpart + (size_t)NZ * NH * NN) - (char*)d_ws);

    k_prep<<<1537, 256, 0, stream>>>(S, x, Wq, Wk, Wv, SM, xb, WTb);
    k_qkv_mfma<<<576, 256, 0, stream>>>(xb, WTb, bq, bk, bv,
                                        angles, SM, Qb, KTb, VTb);
    if (ws_size >= need) {
        k_attn<48 / NZ, true><<<8 * 48 * NZ, 128, 0, stream>>>(Qb, KTb, VTb,
                                                               (float*)Opart, Dpart);
        k_reduce<<<1536, 256, 0, stream>>>(Opart, Dpart, out, NZ);
    } else {
        k_attn<48, false><<<8 * 48, 128, 0, stream>>>(Qb, KTb, VTb, out, nullptr);
    }
}